// Round 6
// baseline (422.073 us; speedup 1.0000x reference)
//
#include <hip/hip_runtime.h>
#include <cmath>

// ---------------------------------------------------------------------------
// GraphTransformerLayer on MI355X (gfx950).
// N=50000 nodes, C=128, H=8 heads, D=16, E=800000 edges (+N self loops).
//
// Pipeline (13 dispatches):
//   zero -> CSR build (count/scan x3/fill)      [edge_index arrives as INT32]
//   k_cast x->bf16 ; k_prep weights -> bf16 [Cout][K]
//   k_qkv   : streaming GEMM, B-in-regs         -> qkv bf16 [N][384]
//   k_attn  : 1 wave/dest node, 4-edge batches  -> ob bf16
//   k_woln  : streaming GEMM + bias+resid+LN1   -> x1f fp32, x1b bf16
//   k_ffn1  : streaming GEMM + gelu             -> hb bf16 [N][512]
//   k_ffn2ln: K=512 streaming GEMM + resid+LN2  -> d_out fp32
//
// GEMM structure (post-mortem of r4/r5: barriers at 1.5 blocks/CU were the
// bottleneck, not LDS conflicts): NO LDS staging, NO __syncthreads in the
// K-loop. Each wave is an independent 32-row x 64-col job; for K=128 the
// whole B-slice lives in 16 bf16x8 regs (64 VGPR); A-fragments are loaded
// straight from global in MFMA layout (16B/lane, 16 rows x 64B segments,
// L1-shared across waves of the block). 32 MFMA per strip, MFMA:VMEM 4:1.
// LN kernels use one tiny 2-wave LDS exchange (block=128 thr).
// ---------------------------------------------------------------------------

typedef short bf16x8 __attribute__((ext_vector_type(8)));
typedef float f32x4 __attribute__((ext_vector_type(4)));

__device__ inline unsigned short f2bf(float f) {
    unsigned int u = __float_as_uint(f);
    u += 0x7fffu + ((u >> 16) & 1u);   // round-to-nearest-even
    return (unsigned short)(u >> 16);
}
__device__ inline float bflo(unsigned int w) { return __uint_as_float(w << 16); }
__device__ inline float bfhi(unsigned int w) { return __uint_as_float(w & 0xffff0000u); }

// ------------------------------- CSR build ---------------------------------

__global__ void k_zero(int* __restrict__ p, int n) {
    int i = blockIdx.x * 256 + threadIdx.x;
    if (i < n) p[i] = 0;
}

__global__ void k_count(const int* __restrict__ ei, int* __restrict__ counts,
                        int E, int N) {
    int e = blockIdx.x * 256 + threadIdx.x;
    if (e >= E + N) return;
    int col = (e < E) ? ei[E + e] : (e - E);
    atomicAdd(&counts[col], 1);
}

__global__ void k_scan1(const int* __restrict__ counts, int* __restrict__ incl,
                        int* __restrict__ bsums, int N) {
    __shared__ int s[256];
    int t = threadIdx.x, i = blockIdx.x * 256 + t;
    int v = (i < N) ? counts[i] : 0;
    s[t] = v; __syncthreads();
    for (int off = 1; off < 256; off <<= 1) {
        int add = (t >= off) ? s[t - off] : 0;
        __syncthreads();
        s[t] += add;
        __syncthreads();
    }
    if (i < N) incl[i] = s[t];
    if (t == 255) bsums[blockIdx.x] = s[255];
}

__global__ void k_scan2(const int* __restrict__ bsums, int* __restrict__ boffs, int NB) {
    __shared__ int s[256];
    int t = threadIdx.x;
    int v = (t < NB) ? bsums[t] : 0;
    s[t] = v; __syncthreads();
    for (int off = 1; off < 256; off <<= 1) {
        int add = (t >= off) ? s[t - off] : 0;
        __syncthreads();
        s[t] += add;
        __syncthreads();
    }
    if (t < NB) boffs[t] = s[t] - v;   // exclusive
}

__global__ void k_scan3(const int* __restrict__ incl, const int* __restrict__ counts,
                        const int* __restrict__ boffs, int* __restrict__ nstart,
                        int* __restrict__ cursor, int N) {
    int i = blockIdx.x * 256 + threadIdx.x;
    if (i >= N) return;
    int st = incl[i] - counts[i] + boffs[blockIdx.x];
    nstart[i] = st;
    cursor[i] = st;
}

__global__ void k_fill(const int* __restrict__ ei, int* __restrict__ cursor,
                       int* __restrict__ csr, int E, int N) {
    int e = blockIdx.x * 256 + threadIdx.x;
    if (e >= E + N) return;
    int row, col;
    if (e < E) { row = ei[e]; col = ei[E + e]; }
    else       { row = col = e - E; }
    int pos = atomicAdd(&cursor[col], 1);
    csr[pos] = row;
}

// ------------------------------ prep (casts) -------------------------------

__global__ void k_cast(const float* __restrict__ x, unsigned short* __restrict__ xb,
                       int total4) {
    int i = blockIdx.x * 256 + threadIdx.x;
    if (i >= total4) return;
    float4 v = ((const float4*)x)[i];
    ushort4 o;
    o.x = f2bf(v.x); o.y = f2bf(v.y); o.z = f2bf(v.z); o.w = f2bf(v.w);
    ((ushort4*)xb)[i] = o;
}

// transpose fp32 [K][Co] -> bf16 [Co][K].  Wq/Wk/Wv land contiguously.
__global__ void k_prep(const float* Wq, const float* Wk, const float* Wv, const float* Wo,
                       const float* Wf1, const float* Wf2,
                       unsigned short* Wqkvt, unsigned short* Wot,
                       unsigned short* Wf1t, unsigned short* Wf2t) {
    int z = blockIdx.y;
    const float* in; unsigned short* out; int K, Co;
    switch (z) {
        case 0: in = Wq;  out = Wqkvt;          K = 128; Co = 128; break;
        case 1: in = Wk;  out = Wqkvt + 16384;  K = 128; Co = 128; break;
        case 2: in = Wv;  out = Wqkvt + 32768;  K = 128; Co = 128; break;
        case 3: in = Wo;  out = Wot;            K = 128; Co = 128; break;
        case 4: in = Wf1; out = Wf1t;           K = 128; Co = 512; break;
        default: in = Wf2; out = Wf2t;          K = 512; Co = 128; break;
    }
    int idx = blockIdx.x * 256 + threadIdx.x;
    if (idx >= K * Co) return;
    int k = idx / Co, c = idx % Co;
    out[c * K + k] = f2bf(in[idx]);
}

// ------------------- streaming GEMM helpers (K=128) ------------------------
// Wave job: 32 rows (m0) x 64 cols (n0). B-slice preloaded into 16 regs.
// A-frag: lane(l16,quad) reads 16B at A[(m0+{0,16}+l16)*128 + ks*32+quad*8].

__device__ inline void load_breg(const unsigned short* __restrict__ Bt, int n0,
                                 int l16, int quad, bf16x8 Breg[4][4]) {
#pragma unroll
    for (int tj = 0; tj < 4; ++tj) {
        const bf16x8* Br = (const bf16x8*)(Bt + (size_t)(n0 + tj * 16 + l16) * 128);
#pragma unroll
        for (int ks = 0; ks < 4; ++ks) Breg[ks][tj] = Br[ks * 4 + quad];
    }
}

__device__ inline void mfma_strip(const unsigned short* __restrict__ A, int m0, int M,
                                  int l16, int quad, const bf16x8 Breg[4][4],
                                  f32x4 acc[2][4]) {
    int ra0 = m0 + l16;      if (ra0 > M - 1) ra0 = M - 1;
    int ra1 = m0 + 16 + l16; if (ra1 > M - 1) ra1 = M - 1;
    const bf16x8* A0 = (const bf16x8*)(A + (size_t)ra0 * 128);
    const bf16x8* A1 = (const bf16x8*)(A + (size_t)ra1 * 128);
#pragma unroll
    for (int ks = 0; ks < 4; ++ks) {
        bf16x8 a0 = A0[ks * 4 + quad];
        bf16x8 a1 = A1[ks * 4 + quad];
#pragma unroll
        for (int tj = 0; tj < 4; ++tj) {
            acc[0][tj] = __builtin_amdgcn_mfma_f32_16x16x32_bf16(a0, Breg[ks][tj], acc[0][tj], 0, 0, 0);
            acc[1][tj] = __builtin_amdgcn_mfma_f32_16x16x32_bf16(a1, Breg[ks][tj], acc[1][tj], 0, 0, 0);
        }
    }
}

// --------------------------- QKV / FFN1 (no LN) ----------------------------
// EPI 0: plain bf16 store.  EPI 1: +bias, gelu(erf), bf16 store.
// Block = NW waves; wave wid covers cols blockIdx.y*NW*64 + wid*64.

template <int EPI, int NW>
__global__ __launch_bounds__(NW * 64) void k_stream(
    const unsigned short* __restrict__ A, const unsigned short* __restrict__ Bt,
    const float* __restrict__ bias, unsigned short* __restrict__ outb,
    int M, int Cout) {
    int tid = threadIdx.x;
    int wid = tid >> 6, lane = tid & 63;
    int quad = lane >> 4, l16 = lane & 15;
    int m0 = blockIdx.x * 32;
    int n0 = blockIdx.y * (NW * 64) + wid * 64;

    bf16x8 Breg[4][4];
    load_breg(Bt, n0, l16, quad, Breg);

    f32x4 acc[2][4];
#pragma unroll
    for (int i = 0; i < 2; ++i)
#pragma unroll
        for (int j = 0; j < 4; ++j) acc[i][j] = {0.f, 0.f, 0.f, 0.f};

    mfma_strip(A, m0, M, l16, quad, Breg, acc);

#pragma unroll
    for (int ti = 0; ti < 2; ++ti)
#pragma unroll
        for (int tj = 0; tj < 4; ++tj) {
            int col = n0 + tj * 16 + l16;
            float bi = (EPI == 1) ? bias[col] : 0.f;
#pragma unroll
            for (int r = 0; r < 4; ++r) {
                int row = m0 + ti * 16 + quad * 4 + r;
                if (row >= M) continue;
                float v = acc[ti][tj][r];
                if constexpr (EPI == 1) {
                    float gg = v + bi;
                    v = 0.5f * gg * (1.f + erff(gg * 0.70710678118f));
                }
                outb[(size_t)row * Cout + col] = f2bf(v);
            }
        }
}

// ------------------- Wo GEMM + bias + resid + LN1 --------------------------
// Block = 128 thr (2 waves): wave wid covers cols wid*64 of 128. K=128.

__global__ __launch_bounds__(128) void k_woln(
    const unsigned short* __restrict__ A, const unsigned short* __restrict__ Bt,
    const float* __restrict__ bias, const float* __restrict__ resid,
    const float* __restrict__ g, const float* __restrict__ b,
    float* __restrict__ outf, unsigned short* __restrict__ outb, int M) {
    __shared__ float pS[2][32], pQ[2][32];
    int tid = threadIdx.x;
    int wid = tid >> 6, lane = tid & 63;
    int quad = lane >> 4, l16 = lane & 15;
    int m0 = blockIdx.x * 32;
    int n0 = wid * 64;

    bf16x8 Breg[4][4];
    load_breg(Bt, n0, l16, quad, Breg);
    f32x4 acc[2][4];
#pragma unroll
    for (int i = 0; i < 2; ++i)
#pragma unroll
        for (int j = 0; j < 4; ++j) acc[i][j] = {0.f, 0.f, 0.f, 0.f};
    mfma_strip(A, m0, M, l16, quad, Breg, acc);

    // bias + residual
#pragma unroll
    for (int tj = 0; tj < 4; ++tj) {
        int col = n0 + tj * 16 + l16;
        float bi = bias[col];
#pragma unroll
        for (int ti = 0; ti < 2; ++ti)
#pragma unroll
            for (int r = 0; r < 4; ++r) {
                int row = m0 + ti * 16 + quad * 4 + r;
                float rv = (row < M) ? resid[(size_t)row * 128 + col] : 0.f;
                acc[ti][tj][r] += bi + rv;
            }
    }
    // row partials over this wave's 64 cols
#pragma unroll
    for (int ti = 0; ti < 2; ++ti)
#pragma unroll
        for (int r = 0; r < 4; ++r) {
            float s = acc[ti][0][r] + acc[ti][1][r] + acc[ti][2][r] + acc[ti][3][r];
            float q = acc[ti][0][r] * acc[ti][0][r] + acc[ti][1][r] * acc[ti][1][r]
                    + acc[ti][2][r] * acc[ti][2][r] + acc[ti][3][r] * acc[ti][3][r];
            s += __shfl_xor(s, 1); q += __shfl_xor(q, 1);
            s += __shfl_xor(s, 2); q += __shfl_xor(q, 2);
            s += __shfl_xor(s, 4); q += __shfl_xor(q, 4);
            s += __shfl_xor(s, 8); q += __shfl_xor(q, 8);
            if (l16 == 0) {
                int lr = ti * 16 + quad * 4 + r;
                pS[wid][lr] = s; pQ[wid][lr] = q;
            }
        }
    __syncthreads();
#pragma unroll
    for (int ti = 0; ti < 2; ++ti)
#pragma unroll
        for (int r = 0; r < 4; ++r) {
            int lr = ti * 16 + quad * 4 + r;
            int row = m0 + lr;
            if (row >= M) continue;
            float s = pS[0][lr] + pS[1][lr];
            float q = pQ[0][lr] + pQ[1][lr];
            float mean = s * 0.0078125f;
            float var = q * 0.0078125f - mean * mean;
            float rs = rsqrtf(var + 1e-5f);
#pragma unroll
            for (int tj = 0; tj < 4; ++tj) {
                int col = n0 + tj * 16 + l16;
                float y = (acc[ti][tj][r] - mean) * rs * g[col] + b[col];
                outf[(size_t)row * 128 + col] = y;
                outb[(size_t)row * 128 + col] = f2bf(y);
            }
        }
}

// ------------------- FFN2 (K=512) + bias + resid + LN2 ---------------------
// Block = 128 thr (2 waves). B-frags streamed from L2 (weights 128KB).

__global__ __launch_bounds__(128) void k_ffn2ln(
    const unsigned short* __restrict__ A, const unsigned short* __restrict__ Bt,
    const float* __restrict__ bias, const float* __restrict__ resid,
    const float* __restrict__ g, const float* __restrict__ b,
    float* __restrict__ outp, int M) {
    __shared__ float pS[2][32], pQ[2][32];
    int tid = threadIdx.x;
    int wid = tid >> 6, lane = tid & 63;
    int quad = lane >> 4, l16 = lane & 15;
    int m0 = blockIdx.x * 32;
    int n0 = wid * 64;

    int ra0 = m0 + l16;      if (ra0 > M - 1) ra0 = M - 1;
    int ra1 = m0 + 16 + l16; if (ra1 > M - 1) ra1 = M - 1;
    const bf16x8* A0 = (const bf16x8*)(A + (size_t)ra0 * 512);
    const bf16x8* A1 = (const bf16x8*)(A + (size_t)ra1 * 512);
    const bf16x8* Brow[4];
#pragma unroll
    for (int tj = 0; tj < 4; ++tj)
        Brow[tj] = (const bf16x8*)(Bt + (size_t)(n0 + tj * 16 + l16) * 512);

    f32x4 acc[2][4];
#pragma unroll
    for (int i = 0; i < 2; ++i)
#pragma unroll
        for (int j = 0; j < 4; ++j) acc[i][j] = {0.f, 0.f, 0.f, 0.f};

#pragma unroll 4
    for (int ks = 0; ks < 16; ++ks) {
        bf16x8 a0 = A0[ks * 4 + quad];
        bf16x8 a1 = A1[ks * 4 + quad];
#pragma unroll
        for (int tj = 0; tj < 4; ++tj) {
            bf16x8 bf = Brow[tj][ks * 4 + quad];
            acc[0][tj] = __builtin_amdgcn_mfma_f32_16x16x32_bf16(a0, bf, acc[0][tj], 0, 0, 0);
            acc[1][tj] = __builtin_amdgcn_mfma_f32_16x16x32_bf16(a1, bf, acc[1][tj], 0, 0, 0);
        }
    }

#pragma unroll
    for (int tj = 0; tj < 4; ++tj) {
        int col = n0 + tj * 16 + l16;
        float bi = bias[col];
#pragma unroll
        for (int ti = 0; ti < 2; ++ti)
#pragma unroll
            for (int r = 0; r < 4; ++r) {
                int row = m0 + ti * 16 + quad * 4 + r;
                float rv = (row < M) ? resid[(size_t)row * 128 + col] : 0.f;
                acc[ti][tj][r] += bi + rv;
            }
    }
#pragma unroll
    for (int ti = 0; ti < 2; ++ti)
#pragma unroll
        for (int r = 0; r < 4; ++r) {
            float s = acc[ti][0][r] + acc[ti][1][r] + acc[ti][2][r] + acc[ti][3][r];
            float q = acc[ti][0][r] * acc[ti][0][r] + acc[ti][1][r] * acc[ti][1][r]
                    + acc[ti][2][r] * acc[ti][2][r] + acc[ti][3][r] * acc[ti][3][r];
            s += __shfl_xor(s, 1); q += __shfl_xor(q, 1);
            s += __shfl_xor(s, 2); q += __shfl_xor(q, 2);
            s += __shfl_xor(s, 4); q += __shfl_xor(q, 4);
            s += __shfl_xor(s, 8); q += __shfl_xor(q, 8);
            if (l16 == 0) {
                int lr = ti * 16 + quad * 4 + r;
                pS[wid][lr] = s; pQ[wid][lr] = q;
            }
        }
    __syncthreads();
#pragma unroll
    for (int ti = 0; ti < 2; ++ti)
#pragma unroll
        for (int r = 0; r < 4; ++r) {
            int lr = ti * 16 + quad * 4 + r;
            int row = m0 + lr;
            if (row >= M) continue;
            float s = pS[0][lr] + pS[1][lr];
            float q = pQ[0][lr] + pQ[1][lr];
            float mean = s * 0.0078125f;
            float var = q * 0.0078125f - mean * mean;
            float rs = rsqrtf(var + 1e-5f);
#pragma unroll
            for (int tj = 0; tj < 4; ++tj) {
                int col = n0 + tj * 16 + l16;
                outp[(size_t)row * 128 + col] = (acc[ti][tj][r] - mean) * rs * g[col] + b[col];
            }
        }
}

// ------------------------------ attention ----------------------------------
// One wave per destination node j; qkv row = [q|k|v] (192 dwords). Lane l
// owns channels (2l,2l+1); lanes 8h..8h+7 hold head h -> 3 shfl_xor reduce.
// 4-edge batches: 8 gathers in flight, one batched online-softmax update.

__global__ __launch_bounds__(256) void k_attn(
    const unsigned int* __restrict__ qkv, const int* __restrict__ nstart,
    const int* __restrict__ counts, const int* __restrict__ csr,
    unsigned int* __restrict__ ob, int N) {
    int j = blockIdx.x * 4 + (threadIdx.x >> 6);
    if (j >= N) return;
    int l = threadIdx.x & 63;

    unsigned int kw = qkv[(size_t)j * 192 + 64 + l];
    float kx = bflo(kw), ky = bfhi(kw);

    int start = nstart[j], cnt = counts[j];
    float m = -3.0e38f, lsum = 0.f, a0 = 0.f, a1 = 0.f;
    int i = 0;
    for (; i + 4 <= cnt; i += 4) {
        int r0 = csr[start + i + 0], r1 = csr[start + i + 1];
        int r2 = csr[start + i + 2], r3 = csr[start + i + 3];
        unsigned int qw0 = qkv[(size_t)r0 * 192 + l];
        unsigned int qw1 = qkv[(size_t)r1 * 192 + l];
        unsigned int qw2 = qkv[(size_t)r2 * 192 + l];
        unsigned int qw3 = qkv[(size_t)r3 * 192 + l];
        unsigned int vw0 = qkv[(size_t)r0 * 192 + 128 + l];
        unsigned int vw1 = qkv[(size_t)r1 * 192 + 128 + l];
        unsigned int vw2 = qkv[(size_t)r2 * 192 + 128 + l];
        unsigned int vw3 = qkv[(size_t)r3 * 192 + 128 + l];

        float p0 = fmaf(bflo(qw0), kx, bfhi(qw0) * ky);
        float p1 = fmaf(bflo(qw1), kx, bfhi(qw1) * ky);
        float p2 = fmaf(bflo(qw2), kx, bfhi(qw2) * ky);
        float p3 = fmaf(bflo(qw3), kx, bfhi(qw3) * ky);
        p0 += __shfl_xor(p0, 1); p1 += __shfl_xor(p1, 1);
        p2 += __shfl_xor(p2, 1); p3 += __shfl_xor(p3, 1);
        p0 += __shfl_xor(p0, 2); p1 += __shfl_xor(p1, 2);
        p2 += __shfl_xor(p2, 2); p3 += __shfl_xor(p3, 2);
        p0 += __shfl_xor(p0, 4); p1 += __shfl_xor(p1, 4);
        p2 += __shfl_xor(p2, 4); p3 += __shfl_xor(p3, 4);
        float s0 = p0 * 0.25f, s1 = p1 * 0.25f, s2 = p2 * 0.25f, s3 = p3 * 0.25f;

        float mn = fmaxf(fmaxf(fmaxf(s0, s1), fmaxf(s2, s3)), m);
        float scale = __expf(m - mn);
        float e0 = __expf(s0 - mn), e1 = __expf(s1 - mn);
        float e2 = __expf(s2 - mn), e3 = __expf(s3 - mn);
        lsum = lsum * scale + ((e0 + e1) + (e2 + e3));
        a0 = a0 * scale + e0 * bflo(vw0) + e1 * bflo(vw1) + e2 * bflo(vw2) + e3 * bflo(vw3);
        a1 = a1 * scale + e0 * bfhi(vw0) + e1 * bfhi(vw1) + e2 * bfhi(vw2) + e3 * bfhi(vw3);
        m = mn;
    }
    for (; i < cnt; ++i) {
        int r = csr[start + i];
        unsigned int qw = qkv[(size_t)r * 192 + l];
        unsigned int vw = qkv[(size_t)r * 192 + 128 + l];
        float p = fmaf(bflo(qw), kx, bfhi(qw) * ky);
        p += __shfl_xor(p, 1);
        p += __shfl_xor(p, 2);
        p += __shfl_xor(p, 4);
        float sc = p * 0.25f;
        float mn = fmaxf(m, sc);
        float scale = __expf(m - mn);
        float e = __expf(sc - mn);
        lsum = lsum * scale + e;
        a0 = a0 * scale + e * bflo(vw);
        a1 = a1 * scale + e * bfhi(vw);
        m = mn;
    }
    float inv = 1.f / (lsum + 1e-8f);
    unsigned int w = ((unsigned int)f2bf(a1 * inv) << 16) | (unsigned int)f2bf(a0 * inv);
    ob[(size_t)j * 64 + l] = w;
}

// -------------------------------- launch -----------------------------------

extern "C" void kernel_launch(void* const* d_in, const int* in_sizes, int n_in,
                              void* d_out, int out_size, void* d_ws, size_t ws_size,
                              hipStream_t stream) {
    const float* x   = (const float*)d_in[0];
    const int* ei    = (const int*)d_in[1];      // int64 materialized as int32
    const float* Wq  = (const float*)d_in[2];
    const float* Wk  = (const float*)d_in[3];
    const float* Wv  = (const float*)d_in[4];
    const float* Wo  = (const float*)d_in[5];
    const float* bo  = (const float*)d_in[6];
    const float* Wf1 = (const float*)d_in[7];
    const float* bf1 = (const float*)d_in[8];
    const float* Wf2 = (const float*)d_in[9];
    const float* bf2 = (const float*)d_in[10];
    const float* g1  = (const float*)d_in[11];
    const float* b1  = (const float*)d_in[12];
    const float* g2  = (const float*)d_in[13];
    const float* b2  = (const float*)d_in[14];

    int N = in_sizes[0] / 128;
    int E = in_sizes[1] / 2;
    int N2 = ((N + 31) / 32) * 32;
    int NE = E + N;

    char* p = (char*)d_ws;
    auto alloc = [&](size_t bytes) -> char* {
        char* r = p;
        p += (bytes + 255) & ~(size_t)255;
        return r;
    };
    // R0: [qkv (N2*384) | ob (N2*128)] bf16, reused as hb [N2][512] for FFN.
    unsigned short* qkv = (unsigned short*)alloc((size_t)N2 * 512 * 2);
    unsigned short* ob  = qkv + (size_t)N2 * 384;
    unsigned short* hb  = qkv;                   // alias (lifetime disjoint)
    // xb aliases x1b: xb dead after QKV GEMM; x1b first written by k_woln.
    unsigned short* x1b = (unsigned short*)alloc((size_t)N2 * 128 * 2);
    unsigned short* xb  = x1b;                   // alias
    float* x1f          = (float*)alloc((size_t)N2 * 128 * 4);
    unsigned short* Wqkvt = (unsigned short*)alloc(3 * 128 * 128 * 2);
    unsigned short* Wot   = (unsigned short*)alloc(128 * 128 * 2);
    unsigned short* Wf1t  = (unsigned short*)alloc(512 * 128 * 2);
    unsigned short* Wf2t  = (unsigned short*)alloc(128 * 512 * 2);
    int* counts = (int*)alloc((size_t)N * 4);
    int* incl   = (int*)alloc((size_t)N * 4);
    int* nstart = (int*)alloc((size_t)N * 4);
    int* cursor = (int*)alloc((size_t)N * 4);
    int* bsums  = (int*)alloc(1024 * 4);
    int* boffs  = (int*)alloc(1024 * 4);
    int* csr    = (int*)alloc((size_t)NE * 4);

    int NB = (N + 255) / 256;          // 196 (<256, one-block scan2)
    int M32 = (N + 31) / 32;           // 1563 row-strips

    k_zero<<<NB, 256, 0, stream>>>(counts, N);
    k_count<<<(NE + 255) / 256, 256, 0, stream>>>(ei, counts, E, N);
    k_scan1<<<NB, 256, 0, stream>>>(counts, incl, bsums, N);
    k_scan2<<<1, 256, 0, stream>>>(bsums, boffs, NB);
    k_scan3<<<NB, 256, 0, stream>>>(incl, counts, boffs, nstart, cursor, N);
    k_fill<<<(NE + 255) / 256, 256, 0, stream>>>(ei, cursor, csr, E, N);

    k_cast<<<((N * 128 / 4) + 255) / 256, 256, 0, stream>>>(x, xb, N * 128 / 4);
    k_prep<<<dim3(256, 6), 256, 0, stream>>>(Wq, Wk, Wv, Wo, Wf1, Wf2,
                                             Wqkvt, Wot, Wf1t, Wf2t);

    // QKV: xb [N][128] @ Wqkvt [384][128] -> qkv [N][384]; 3 waves x 64 cols x2
    k_stream<0, 3><<<dim3(M32, 2), 192, 0, stream>>>(xb, Wqkvt, nullptr, qkv, N, 384);

    k_attn<<<(N + 3) / 4, 256, 0, stream>>>((const unsigned int*)qkv, nstart,
                                            counts, csr, (unsigned int*)ob, N);

    // Wo + bias + residual(x) + LN1 -> x1f fp32, x1b bf16
    k_woln<<<dim3(M32), 128, 0, stream>>>(ob, Wot, bo, x, g1, b1, x1f, x1b, N);

    // FFN1 + gelu -> hb (aliases qkv|ob, both dead)
    k_stream<1, 4><<<dim3(M32, 2), 256, 0, stream>>>(x1b, Wf1t, bf1, hb, N, 512);

    // FFN2 (K=512) + bias + residual(x1f) + LN2 -> d_out fp32
    k_ffn2ln<<<dim3(M32), 128, 0, stream>>>(hb, Wf2t, bf2, x1f, g2, b2,
                                            (float*)d_out, N);
}